// Round 2
// baseline (338.187 us; speedup 1.0000x reference)
//
#include <hip/hip_runtime.h>
#include <stdint.h>

// GatingLayer: logits = x[16384,3072] . W[8,3072]^T + b[8]; softmax(8);
// top-2 (lowest-index tie-break); softmax over the selected 2.
// d_out = values (fp32 x 32768) ++ indices-as-float (x 32768).
//
// Phase 1: async global->LDS staging (global_load_lds width=16), double
// buffer, fine-grained s_waitcnt vmcnt(8) + raw s_barrier (never drain the
// prefetch queue mid-loop). Thread==token, W via wave-uniform scalar loads,
// split-D (NDB=8) combined with fp32 atomics.

#define NTOK   16384
#define DMODEL 3072
#define NEXP   8
#define NDB    8                  // d-split across blockIdx.y
#define DCH    (DMODEL / NDB)     // 384 d per block
#define DS     32                 // d per stage
#define NST    (DCH / DS)         // 12 stages
#define TPB    256                // threads per block == tokens per block

typedef __attribute__((address_space(1))) const void gvoid;
typedef __attribute__((address_space(3))) void lvoid;

__global__ __launch_bounds__(TPB) void gate_logits_kernel(
    const float* __restrict__ x, const float* __restrict__ W,
    float* __restrict__ logits) {
  // 2 x 32 KB stage buffers, lane-order layout (global_load_lds forbids
  // padding: LDS dest = wave-uniform base + lane*16).
  __shared__ float4 sbuf[2][2048];

  const int tid = threadIdx.x;
  const int wave = tid >> 6;
  const int lane = tid & 63;
  const int tokBase = blockIdx.x * TPB;
  const int dBase = blockIdx.y * DCH;

  // Issue one stage (32 KB = 32 chunks of 1 KB; 8 DMA instrs per wave).
  // Source-swizzle: LDS slot j4 of token t holds global d-chunk (j4 ^ (t&7))
  // so compute-side row reads spread over 8 bank groups instead of 1.
  auto issue_stage = [&](int s, int b) {
    const int d0 = dBase + s * DS;
#pragma unroll
    for (int k = 0; k < 8; ++k) {
      const int c = wave * 8 + k;          // chunk [0,32)
      const int g = c * 64 + lane;         // flat float4 slot [0,2048)
      const int tok = g >> 3;              // token within block [0,256)
      const int slot = g & 7;              // LDS j4 slot
      const int d4 = slot ^ (tok & 7);     // swizzled global d-chunk
      const float* gp =
          x + (size_t)(tokBase + tok) * DMODEL + d0 + d4 * 4;
      __builtin_amdgcn_global_load_lds((gvoid*)gp, (lvoid*)&sbuf[b][c * 64],
                                       16, 0, 0);
    }
  };

  float acc[NEXP];
#pragma unroll
  for (int e = 0; e < NEXP; ++e) acc[e] = 0.f;

  issue_stage(0, 0);
  issue_stage(1, 1);

  for (int s = 0; s < NST; ++s) {
    // Wait for THIS stage's 8 DMA instrs (the oldest 8 of <=16 outstanding);
    // the next stage's 8 stay in flight across the barrier.
    if (s < NST - 1) {
      asm volatile("s_waitcnt vmcnt(8)\n\ts_barrier" ::: "memory");
    } else {
      asm volatile("s_waitcnt vmcnt(0)\n\ts_barrier" ::: "memory");
    }

    const int b = s & 1;
    const int d0 = dBase + s * DS;
    const float4* row = &sbuf[b][tid * 8];
#pragma unroll
    for (int q = 0; q < 8; ++q) {
      const float4 xv = row[q ^ (tid & 7)];  // un-swizzle
      const int dw = d0 + q * 4;
#pragma unroll
      for (int e = 0; e < NEXP; ++e) {
        const float* wr = &W[e * DMODEL + dw];  // wave-uniform -> s_load
        acc[e] = fmaf(xv.x, wr[0],
                 fmaf(xv.y, wr[1],
                 fmaf(xv.z, wr[2],
                 fmaf(xv.w, wr[3], acc[e]))));
      }
    }

    // All reads of buffer b retired before anyone overwrites it.
    asm volatile("s_waitcnt lgkmcnt(0)\n\ts_barrier" ::: "memory");
    if (s + 2 < NST) issue_stage(s + 2, b);
  }

#pragma unroll
  for (int e = 0; e < NEXP; ++e) {
    atomicAdd(&logits[(size_t)(tokBase + tid) * NEXP + e], acc[e]);
  }
}

// Phase 2: bias + softmax(8) + top-2 + renorm softmax(2). One thread/token.
// 64-thread blocks -> 256 blocks so all CUs participate.
__global__ __launch_bounds__(64) void gate_topk_kernel(
    const float* __restrict__ logits, const float* __restrict__ bias,
    float* __restrict__ out) {
  const int t = blockIdx.x * 64 + threadIdx.x;
  if (t >= NTOK) return;

  float l[NEXP];
#pragma unroll
  for (int e = 0; e < NEXP; ++e) l[e] = logits[(size_t)t * NEXP + e] + bias[e];

  float m = l[0];
#pragma unroll
  for (int e = 1; e < NEXP; ++e) m = fmaxf(m, l[e]);

  float p[NEXP];
  float ssum = 0.f;
#pragma unroll
  for (int e = 0; e < NEXP; ++e) {
    p[e] = expf(l[e] - m);
    ssum += p[e];
  }
  const float inv = 1.f / ssum;
#pragma unroll
  for (int e = 0; e < NEXP; ++e) p[e] *= inv;

  // top-2, first-occurrence on ties (matches jax.lax.top_k stable order).
  int i1 = 0;
  float v1 = p[0];
#pragma unroll
  for (int e = 1; e < NEXP; ++e) {
    if (p[e] > v1) { v1 = p[e]; i1 = e; }
  }
  int i2 = -1;
  float v2 = -1.f;
#pragma unroll
  for (int e = 0; e < NEXP; ++e) {
    if (e == i1) continue;
    if (p[e] > v2) { v2 = p[e]; i2 = e; }
  }

  const float e2 = expf(v2 - v1);  // v1 >= v2
  const float r = 1.f / (1.f + e2);

  out[(size_t)t * 2 + 0] = r;
  out[(size_t)t * 2 + 1] = e2 * r;
  out[2 * NTOK + (size_t)t * 2 + 0] = (float)i1;
  out[2 * NTOK + (size_t)t * 2 + 1] = (float)i2;
}

extern "C" void kernel_launch(void* const* d_in, const int* in_sizes, int n_in,
                              void* d_out, int out_size, void* d_ws,
                              size_t ws_size, hipStream_t stream) {
  const float* x = (const float*)d_in[0];
  const float* W = (const float*)d_in[1];
  const float* b = (const float*)d_in[2];
  float* out = (float*)d_out;
  float* logits = (float*)d_ws;  // NTOK * NEXP fp32 = 512 KB

  // ws is re-poisoned to 0xAA before every launch; zero the accumulator.
  hipMemsetAsync(d_ws, 0, (size_t)NTOK * NEXP * sizeof(float), stream);

  dim3 grid1(NTOK / TPB, NDB);
  gate_logits_kernel<<<grid1, TPB, 0, stream>>>(x, W, logits);

  gate_topk_kernel<<<NTOK / 64, 64, 0, stream>>>(logits, b, out);
}

// Round 3
// 296.823 us; speedup vs baseline: 1.1394x; 1.1394x over previous
//
#include <hip/hip_runtime.h>
#include <stdint.h>

// GatingLayer: logits = x[16384,3072] . W[8,3072]^T + b[8]; softmax(8);
// top-2 (lowest-index tie-break); softmax over the selected 2.
// d_out = values (fp32 x 32768) ++ indices-as-float (x 32768).
//
// Phase 1 design (R2): no global loads and no barriers in the K-loop.
//  - W chunk staged to LDS once per block, read into registers per stage
//    (8 broadcast ds_read_b128 per wave per stage).
//  - lane = sl*8+tg: tg = token-in-group, sl = 4-float d-slice. Each lane
//    accumulates 8 tokens x 8 experts over its slice; slices reduced at the
//    end with a 3-round shfl_xor butterfly.
//  - x staged via wave-PRIVATE double-buffered global_load_lds (8 KB/stage);
//    vmcnt is per-wave so s_waitcnt vmcnt(8) alone gates the pipeline.

#define NTOK   16384
#define DMODEL 3072
#define NEXP   8
#define NDB    8                  // d-split across blockIdx.y
#define DCH    (DMODEL / NDB)     // 384 d per block
#define DS     32                 // d per stage
#define NST    (DCH / DS)         // 12 stages
#define TPB    256                // 4 waves; each wave owns 64 tokens

typedef __attribute__((address_space(1))) const void gvoid;
typedef __attribute__((address_space(3))) void lvoid;

__global__ __launch_bounds__(TPB) void gate_logits_kernel(
    const float* __restrict__ x, const float* __restrict__ W,
    float* __restrict__ logits) {
  // Wave-private x stage buffers: [wave][buf][64 tok * 8 slots] float4 = 64 KB.
  __shared__ float4 sx[4][2][512];
  // W chunk for this block's d-range, natural [e][DCH] layout = 12 KB.
  __shared__ float sw[NEXP * DCH];

  const int tid = threadIdx.x;
  const int wv = tid >> 6;
  const int lane = tid & 63;
  const int sl = lane >> 3;       // d-slice [0,8)
  const int tg = lane & 7;        // token-in-group [0,8)
  const int tokBase = blockIdx.x * TPB;
  const int dBase = blockIdx.y * DCH;

  // ---- Stage W chunk into LDS (once) ----
  for (int f = tid; f < NEXP * DCH / 4; f += TPB) {  // 768 float4
    const int e = f / (DCH / 4);
    const int j = f % (DCH / 4);
    const float4 v = *(const float4*)&W[e * DMODEL + dBase + j * 4];
    *(float4*)&sw[e * DCH + j * 4] = v;
  }
  __syncthreads();  // the only block-wide barrier

  const float* xw = x + (size_t)(tokBase + wv * 64) * DMODEL + dBase;

  // Issue one 8 KB stage for this wave: 8 DMA instrs, each 64 lanes x 16 B
  // covering 8 tokens x 128 B. LDS layout: float4 index = tok*8 + slot,
  // slot = d-chunk (no swizzle needed; the (tg,sl) read pattern is spread).
  auto issue = [&](int s, int b) {
    const int d0 = s * DS;
#pragma unroll
    for (int k = 0; k < 8; ++k) {
      const int g = k * 64 + lane;
      const int tok = g >> 3;
      const int slot = g & 7;
      const float* gp = xw + (size_t)tok * DMODEL + d0 + slot * 4;
      __builtin_amdgcn_global_load_lds((gvoid*)gp, (lvoid*)&sx[wv][b][k * 64],
                                       16, 0, 0);
    }
  };

  float acc[8][NEXP];  // [token-pass p][expert]
#pragma unroll
  for (int p = 0; p < 8; ++p)
#pragma unroll
    for (int e = 0; e < NEXP; ++e) acc[p][e] = 0.f;

  issue(0, 0);
  issue(1, 1);

#pragma unroll 2
  for (int s = 0; s < NST; ++s) {
    // Stage s's 8 DMA are the oldest outstanding; leave stage s+1 in flight.
    if (s == NST - 1) {
      asm volatile("s_waitcnt vmcnt(0)" ::: "memory");
    } else {
      asm volatile("s_waitcnt vmcnt(8)" ::: "memory");
    }

    const int b = s & 1;

    // W for this stage: lane's slice, all 8 experts -> 32 stationary VGPRs.
    // 8 unique addresses per instr (one per sl), broadcast to 8 lanes each,
    // distinct bank groups -> conflict-free.
    float4 w4[NEXP];
#pragma unroll
    for (int e = 0; e < NEXP; ++e)
      w4[e] = *(const float4*)&sw[e * DCH + s * DS + sl * 4];

    const float4* buf = sx[wv][b];
#pragma unroll
    for (int p = 0; p < 8; ++p) {
      const float4 xv = buf[(p * 8 + tg) * 8 + sl];
#pragma unroll
      for (int e = 0; e < NEXP; ++e) {
        acc[p][e] = fmaf(xv.x, w4[e].x,
                    fmaf(xv.y, w4[e].y,
                    fmaf(xv.z, w4[e].z,
                    fmaf(xv.w, w4[e].w, acc[p][e]))));
      }
    }

    // My reads of buffer b have retired before DMA overwrites it.
    if (s + 2 < NST) {
      asm volatile("s_waitcnt lgkmcnt(0)" ::: "memory");
      issue(s + 2, b);
    }
  }

  // ---- Reduce over d-slices: butterfly on lane bits 3..5 ----
#pragma unroll
  for (int p = 0; p < 8; ++p)
#pragma unroll
    for (int e = 0; e < NEXP; ++e) {
      float v = acc[p][e];
      v += __shfl_xor(v, 8, 64);
      v += __shfl_xor(v, 16, 64);
      v += __shfl_xor(v, 32, 64);
      acc[p][e] = v;  // every lane now holds the full (p,tg,e) sum
    }

  // Lane `lane` owns token (lane>>3)*8 + (lane&7) == p=sl, tg: select p==sl.
  float out8[NEXP];
#pragma unroll
  for (int p = 0; p < 8; ++p) {
    if (p == sl) {
#pragma unroll
      for (int e = 0; e < NEXP; ++e) out8[e] = acc[p][e];
    }
  }

  float* lp = &logits[(size_t)(tokBase + wv * 64 + lane) * NEXP];
#pragma unroll
  for (int e = 0; e < NEXP; ++e) atomicAdd(lp + e, out8[e]);
}

// Phase 2: bias + softmax(8) + top-2 + renorm softmax(2). One thread/token.
__global__ __launch_bounds__(64) void gate_topk_kernel(
    const float* __restrict__ logits, const float* __restrict__ bias,
    float* __restrict__ out) {
  const int t = blockIdx.x * 64 + threadIdx.x;
  if (t >= NTOK) return;

  float l[NEXP];
#pragma unroll
  for (int e = 0; e < NEXP; ++e) l[e] = logits[(size_t)t * NEXP + e] + bias[e];

  float m = l[0];
#pragma unroll
  for (int e = 1; e < NEXP; ++e) m = fmaxf(m, l[e]);

  float p[NEXP];
  float ssum = 0.f;
#pragma unroll
  for (int e = 0; e < NEXP; ++e) {
    p[e] = expf(l[e] - m);
    ssum += p[e];
  }
  const float inv = 1.f / ssum;
#pragma unroll
  for (int e = 0; e < NEXP; ++e) p[e] *= inv;

  // top-2, first-occurrence on ties (matches jax.lax.top_k stable order).
  int i1 = 0;
  float v1 = p[0];
#pragma unroll
  for (int e = 1; e < NEXP; ++e) {
    if (p[e] > v1) { v1 = p[e]; i1 = e; }
  }
  int i2 = -1;
  float v2 = -1.f;
#pragma unroll
  for (int e = 0; e < NEXP; ++e) {
    if (e == i1) continue;
    if (p[e] > v2) { v2 = p[e]; i2 = e; }
  }

  const float e2 = expf(v2 - v1);  // v1 >= v2
  const float r = 1.f / (1.f + e2);

  out[(size_t)t * 2 + 0] = r;
  out[(size_t)t * 2 + 1] = e2 * r;
  out[2 * NTOK + (size_t)t * 2 + 0] = (float)i1;
  out[2 * NTOK + (size_t)t * 2 + 1] = (float)i2;
}

extern "C" void kernel_launch(void* const* d_in, const int* in_sizes, int n_in,
                              void* d_out, int out_size, void* d_ws,
                              size_t ws_size, hipStream_t stream) {
  const float* x = (const float*)d_in[0];
  const float* W = (const float*)d_in[1];
  const float* b = (const float*)d_in[2];
  float* out = (float*)d_out;
  float* logits = (float*)d_ws;  // NTOK * NEXP fp32 = 512 KB

  // ws is re-poisoned to 0xAA before every launch; zero the accumulator.
  hipMemsetAsync(d_ws, 0, (size_t)NTOK * NEXP * sizeof(float), stream);

  dim3 grid1(NTOK / TPB, NDB);
  gate_logits_kernel<<<grid1, TPB, 0, stream>>>(x, W, logits);

  gate_topk_kernel<<<NTOK / 64, 64, 0, stream>>>(logits, b, out);
}

// Round 4
// 285.371 us; speedup vs baseline: 1.1851x; 1.0401x over previous
//
#include <hip/hip_runtime.h>
#include <stdint.h>

// GatingLayer: logits = x[16384,3072] . W[8,3072]^T + b[8]; softmax(8);
// top-2 (lowest-index tie-break); softmax over the selected 2.
// d_out = values (fp32 x 32768) ++ indices-as-float (x 32768).
//
// R3 design: x goes global -> REGISTERS (no LDS, no barriers, no DMA-alias
// hazards -- compiler tracks register loads with precise per-reg vmcnt).
// Lane map (sl,tg): lane = sl*8+tg; lane owns d-slice sl (4 floats) of
// 8 tokens (p*8+tg). 2-stage register double buffer over 12 K-stages.
// W chunk lives in LDS (lgkm domain, independent of the x vmcnt domain).
// Split-D partials written to d_ws (no atomics, no memset), summed in topk.

#define NTOK   16384
#define DMODEL 3072
#define NEXP   8
#define NDB    8                  // d-split across blockIdx.y
#define DCH    (DMODEL / NDB)     // 384 d per block
#define DS     32                 // d per stage
#define NST    (DCH / DS)         // 12 stages
#define TPB    256                // 4 waves; each wave owns 64 tokens

__global__ __launch_bounds__(TPB) void gate_logits_kernel(
    const float* __restrict__ x, const float* __restrict__ W,
    float* __restrict__ part) {
  __shared__ float sw[NEXP * DCH];  // 12 KB: this block's W d-chunk

  const int tid = threadIdx.x;
  const int wv = tid >> 6;
  const int lane = tid & 63;
  const int sl = lane >> 3;       // d-slice [0,8)
  const int tg = lane & 7;        // token-in-group [0,8)
  const int tokBase = blockIdx.x * TPB;
  const int dBase = blockIdx.y * DCH;

  // Stage W chunk into LDS once (768 float4 over 256 threads).
  for (int f = tid; f < NEXP * DCH / 4; f += TPB) {
    const int e = f / (DCH / 4);
    const int j = f - e * (DCH / 4);
    *(float4*)&sw[e * DCH + j * 4] =
        *(const float4*)&W[e * DMODEL + dBase + j * 4];
  }
  __syncthreads();  // only block-wide barrier in the kernel

  // Per-lane global pointers: 8 tokens, this lane's d-slice.
  const float* p8[8];
#pragma unroll
  for (int p = 0; p < 8; ++p)
    p8[p] = x + (size_t)(tokBase + wv * 64 + p * 8 + tg) * DMODEL + dBase +
            sl * 4;

  float acc[8][NEXP];
#pragma unroll
  for (int p = 0; p < 8; ++p)
#pragma unroll
    for (int e = 0; e < NEXP; ++e) acc[p][e] = 0.f;

  float4 xa[8], xb[8];
#pragma unroll
  for (int p = 0; p < 8; ++p) xa[p] = *(const float4*)(p8[p]);  // stage 0

#pragma unroll 1
  for (int s = 0; s < NST; s += 2) {
    // Prefetch stage s+1 (register dbuf; compiler emits precise vmcnt(N)).
#pragma unroll
    for (int p = 0; p < 8; ++p)
      xb[p] = *(const float4*)(p8[p] + (s + 1) * DS);

    // W for stage s: 8 broadcast ds_read_b128, conflict-free.
    float4 w4[NEXP];
#pragma unroll
    for (int e = 0; e < NEXP; ++e)
      w4[e] = *(const float4*)&sw[e * DCH + s * DS + sl * 4];

#pragma unroll
    for (int p = 0; p < 8; ++p) {
      const float4 xv = xa[p];
#pragma unroll
      for (int e = 0; e < NEXP; ++e)
        acc[p][e] = fmaf(xv.x, w4[e].x,
                    fmaf(xv.y, w4[e].y,
                    fmaf(xv.z, w4[e].z,
                    fmaf(xv.w, w4[e].w, acc[p][e]))));
    }

    if (s + 2 < NST) {
#pragma unroll
      for (int p = 0; p < 8; ++p)
        xa[p] = *(const float4*)(p8[p] + (s + 2) * DS);
    }

#pragma unroll
    for (int e = 0; e < NEXP; ++e)
      w4[e] = *(const float4*)&sw[e * DCH + (s + 1) * DS + sl * 4];

#pragma unroll
    for (int p = 0; p < 8; ++p) {
      const float4 xv = xb[p];
#pragma unroll
      for (int e = 0; e < NEXP; ++e)
        acc[p][e] = fmaf(xv.x, w4[e].x,
                    fmaf(xv.y, w4[e].y,
                    fmaf(xv.z, w4[e].z,
                    fmaf(xv.w, w4[e].w, acc[p][e]))));
    }
  }

  // Reduce over d-slices (lane bits 3..5 butterfly).
#pragma unroll
  for (int p = 0; p < 8; ++p)
#pragma unroll
    for (int e = 0; e < NEXP; ++e) {
      float v = acc[p][e];
      v += __shfl_xor(v, 8, 64);
      v += __shfl_xor(v, 16, 64);
      v += __shfl_xor(v, 32, 64);
      acc[p][e] = v;
    }

  // Lane owns token (lane>>3)*8 + (lane&7): select p == sl.
  float out8[NEXP];
#pragma unroll
  for (int p = 0; p < 8; ++p) {
    if (p == sl) {
#pragma unroll
      for (int e = 0; e < NEXP; ++e) out8[e] = acc[p][e];
    }
  }

  float* op =
      part + ((size_t)blockIdx.y * NTOK + tokBase + wv * 64 + lane) * NEXP;
  *(float4*)op = make_float4(out8[0], out8[1], out8[2], out8[3]);
  *(float4*)(op + 4) = make_float4(out8[4], out8[5], out8[6], out8[7]);
}

// Phase 2: sum NDB partials + bias + softmax(8) + top-2 + renorm softmax(2).
__global__ __launch_bounds__(64) void gate_topk_kernel(
    const float* __restrict__ part, const float* __restrict__ bias,
    float* __restrict__ out) {
  const int t = blockIdx.x * 64 + threadIdx.x;
  if (t >= NTOK) return;

  float l[NEXP];
#pragma unroll
  for (int e = 0; e < NEXP; ++e) l[e] = bias[e];
#pragma unroll
  for (int p = 0; p < NDB; ++p) {
    const float* pp = &part[(size_t)p * NTOK * NEXP + (size_t)t * NEXP];
    const float4 a = *(const float4*)pp;
    const float4 b = *(const float4*)(pp + 4);
    l[0] += a.x; l[1] += a.y; l[2] += a.z; l[3] += a.w;
    l[4] += b.x; l[5] += b.y; l[6] += b.z; l[7] += b.w;
  }

  float m = l[0];
#pragma unroll
  for (int e = 1; e < NEXP; ++e) m = fmaxf(m, l[e]);

  float p8[NEXP];
  float ssum = 0.f;
#pragma unroll
  for (int e = 0; e < NEXP; ++e) {
    p8[e] = expf(l[e] - m);
    ssum += p8[e];
  }
  const float inv = 1.f / ssum;
#pragma unroll
  for (int e = 0; e < NEXP; ++e) p8[e] *= inv;

  // top-2, first-occurrence on ties (matches jax.lax.top_k stable order).
  int i1 = 0;
  float v1 = p8[0];
#pragma unroll
  for (int e = 1; e < NEXP; ++e) {
    if (p8[e] > v1) { v1 = p8[e]; i1 = e; }
  }
  int i2 = -1;
  float v2 = -1.f;
#pragma unroll
  for (int e = 0; e < NEXP; ++e) {
    if (e == i1) continue;
    if (p8[e] > v2) { v2 = p8[e]; i2 = e; }
  }

  const float e2 = expf(v2 - v1);  // v1 >= v2
  const float r = 1.f / (1.f + e2);

  out[(size_t)t * 2 + 0] = r;
  out[(size_t)t * 2 + 1] = e2 * r;
  out[2 * NTOK + (size_t)t * 2 + 0] = (float)i1;
  out[2 * NTOK + (size_t)t * 2 + 1] = (float)i2;
}

extern "C" void kernel_launch(void* const* d_in, const int* in_sizes, int n_in,
                              void* d_out, int out_size, void* d_ws,
                              size_t ws_size, hipStream_t stream) {
  const float* x = (const float*)d_in[0];
  const float* W = (const float*)d_in[1];
  const float* b = (const float*)d_in[2];
  float* out = (float*)d_out;
  float* part = (float*)d_ws;  // NDB * NTOK * NEXP fp32 = 4 MB, fully written

  dim3 grid1(NTOK / TPB, NDB);
  gate_logits_kernel<<<grid1, TPB, 0, stream>>>(x, W, part);

  gate_topk_kernel<<<NTOK / 64, 64, 0, stream>>>(part, b, out);
}